// Round 5
// baseline (324.395 us; speedup 1.0000x reference)
//
#include <hip/hip_runtime.h>
#include <math.h>

#define HIDDEN 1024
#define SEQ 2048
#define NF 94
#define PI 256
#define NUM_TOKEN 5

// clang-native 16B vector (usable with __builtin_nontemporal_store)
typedef float vfloat4 __attribute__((ext_vector_type(4)));

// gelu exact (erf form), matches jax.nn.gelu(approximate=False) in fp32
__device__ __forceinline__ float gelu_exact(float a) {
    return 0.5f * a * (1.0f + erff(a * 0.70710678118654752f));
}

// Cold path: numeric-feature MLP + projection LayerNorm, adds result into x.
// Taken by ~0-2 waves out of 8192 (ids==5 is ~1/50k). Copied VERBATIM from
// the verified kernel; spills under the 128-VGPR cap are statistically free.
__device__ __forceinline__ void numeric_add(float x[4][4], float vraw, int fmt,
                                            int lane, int col0,
                                            const float* __restrict__ w1,
                                            const float* __restrict__ b1,
                                            const float* __restrict__ w2,
                                            const float* __restrict__ b2,
                                            const float* __restrict__ plng,
                                            const float* __restrict__ plnb)
{
    const double    v    = (double)vraw;
    const double    av   = fabs(v);
    const long long bits = __double_as_longlong(v);
    const double    fl   = floor(av);

    // ---- features: lane k owns feat[k] (f0) and feat[64+k] (f1) ----
    float f0 = (lane < 63 && ((bits >> lane) & 1LL)) ? 1.0f : 0.0f;
    float f1 = 0.0f;
    if (lane < 10) {
        const int units = (int)fmin(fmax(fmod(fl, 10.0), 0.0), 9.0);
        f1 = (lane == units) ? 1.0f : 0.0f;
    } else if (lane < 20) {
        const int tens = (int)fmin(fmax(fmod(floor(fl / 10.0), 10.0), 0.0), 9.0);
        f1 = (lane - 10 == tens) ? 1.0f : 0.0f;
    } else if (lane < 30) {
        switch (lane - 20) {
            case 0: f1 = (float)log(av + 1e-6); break;
            case 1: f1 = (v > 0.0) ? 1.0f : ((v < 0.0) ? -1.0f : 0.0f); break;
            case 2: f1 = (av > 1e-6) ? (float)floor(log10(fmax(av, 1e-300))) : 0.0f; break;
            case 3: f1 = (av == fl) ? 1.0f : 0.0f; break;
            case 4: f1 = (v > 0.0) ? 1.0f : 0.0f; break;
            case 5: f1 = (v == 0.0) ? 1.0f : 0.0f; break;
            case 6: f1 = (v < 0.0) ? 1.0f : 0.0f; break;
            case 7: {
                const bool   pos_int = (v == floor(v)) && (v > 0.0);
                const double l2      = log2(fmax(v, 1.0));
                f1 = (pos_int && (l2 == floor(l2))) ? 1.0f : 0.0f;
                break;
            }
            case 8: f1 = (fmt == 0) ? 1.0f : 0.0f; break;
            case 9: f1 = (fmt == 1) ? 1.0f : 0.0f; break;
        }
    }

    // ---- h[o] = gelu(feats @ w1 + b1), lane owns o = lane + 64*i ----
    float acc[4] = { b1[lane], b1[lane + 64], b1[lane + 128], b1[lane + 192] };
    for (int k = 0; k < 64; ++k) {
        const float  fk  = __shfl(f0, k, 64);
        const float* col = w1 + k * PI;
        acc[0] = fmaf(fk, col[lane],       acc[0]);
        acc[1] = fmaf(fk, col[lane + 64],  acc[1]);
        acc[2] = fmaf(fk, col[lane + 128], acc[2]);
        acc[3] = fmaf(fk, col[lane + 192], acc[3]);
    }
    for (int k = 0; k < NF - 64; ++k) {
        const float  fk  = __shfl(f1, k, 64);
        const float* col = w1 + (64 + k) * PI;
        acc[0] = fmaf(fk, col[lane],       acc[0]);
        acc[1] = fmaf(fk, col[lane + 64],  acc[1]);
        acc[2] = fmaf(fk, col[lane + 128], acc[2]);
        acc[3] = fmaf(fk, col[lane + 192], acc[3]);
    }
    float h[4];
    #pragma unroll
    for (int i = 0; i < 4; ++i) h[i] = gelu_exact(acc[i]);

    // ---- n = h @ w2 + b2, lane owns d = j*256 + lane*4 + c ----
    float n[4][4];
    #pragma unroll
    for (int j = 0; j < 4; ++j) {
        const float4 bb = *(const float4*)(b2 + j * 256 + col0);
        n[j][0] = bb.x; n[j][1] = bb.y; n[j][2] = bb.z; n[j][3] = bb.w;
    }
    #pragma unroll
    for (int i = 0; i < 4; ++i) {          // h register block (static idx)
        for (int kk = 0; kk < 64; ++kk) {
            const float  hk  = __shfl(h[i], kk, 64);
            const float* row = w2 + (size_t)(i * 64 + kk) * HIDDEN;
            #pragma unroll
            for (int j = 0; j < 4; ++j) {
                const float4 w = *(const float4*)(row + j * 256 + col0);
                n[j][0] = fmaf(hk, w.x, n[j][0]);
                n[j][1] = fmaf(hk, w.y, n[j][1]);
                n[j][2] = fmaf(hk, w.z, n[j][2]);
                n[j][3] = fmaf(hk, w.w, n[j][3]);
            }
        }
    }

    // ---- projection LayerNorm (wave butterfly) ----
    float sm = 0.0f, sq = 0.0f;
    #pragma unroll
    for (int j = 0; j < 4; ++j)
        #pragma unroll
        for (int c = 0; c < 4; ++c) { sm += n[j][c]; sq += n[j][c] * n[j][c]; }
    #pragma unroll
    for (int off = 32; off > 0; off >>= 1) {
        sm += __shfl_xor(sm, off, 64);
        sq += __shfl_xor(sq, off, 64);
    }
    const float mu   = sm * (1.0f / HIDDEN);
    const float var  = sq * (1.0f / HIDDEN) - mu * mu;
    const float rstd = rsqrtf(var + 1e-12f);
    #pragma unroll
    for (int j = 0; j < 4; ++j) {
        const float4 g4 = *(const float4*)(plng + j * 256 + col0);
        const float4 b4 = *(const float4*)(plnb + j * 256 + col0);
        x[j][0] += (n[j][0] - mu) * rstd * g4.x + b4.x;
        x[j][1] += (n[j][1] - mu) * rstd * g4.y + b4.y;
        x[j][2] += (n[j][2] - mu) * rstd * g4.z + b4.z;
        x[j][3] += (n[j][3] - mu) * rstd * g4.w + b4.w;
    }
}

// Final LayerNorm (wave butterfly) + nontemporal store of one token row.
__device__ __forceinline__ void final_ln_store(float x[4][4], int lane, int col0,
                                               const float* __restrict__ lng,
                                               const float* __restrict__ lnb,
                                               float* __restrict__ orow)
{
    float sm = 0.0f, sq = 0.0f;
    #pragma unroll
    for (int j = 0; j < 4; ++j)
        #pragma unroll
        for (int c = 0; c < 4; ++c) { sm += x[j][c]; sq += x[j][c] * x[j][c]; }
    #pragma unroll
    for (int off = 32; off > 0; off >>= 1) {
        sm += __shfl_xor(sm, off, 64);
        sq += __shfl_xor(sq, off, 64);
    }
    const float mu   = sm * (1.0f / HIDDEN);
    const float var  = sq * (1.0f / HIDDEN) - mu * mu;
    const float rstd = rsqrtf(var + 1e-12f);

    #pragma unroll
    for (int j = 0; j < 4; ++j) {
        const int off = j * 256 + col0;
        const float4 g4 = *(const float4*)(lng + off);
        const float4 b4 = *(const float4*)(lnb + off);
        vfloat4 o;
        o.x = (x[j][0] - mu) * rstd * g4.x + b4.x;
        o.y = (x[j][1] - mu) * rstd * g4.y + b4.y;
        o.z = (x[j][2] - mu) * rstd * g4.z + b4.z;
        o.w = (x[j][3] - mu) * rstd * g4.w + b4.w;
        __builtin_nontemporal_store(o, (vfloat4*)(orow + off));
    }
}

// Two tokens per wave, all 20 global loads issued up front (4 Ww + 4 Wp per
// token + 4 shared Wt), so token 0's LN/store overlaps token 1's in-flight
// loads via the compiler's counted vmcnt. This doubles per-wave memory-level
// parallelism at unchanged occupancy/traffic — the single-variable test that
// separates "latency-bound" from "random-gather HW BW floor".
//   r0/r4 (12 loads/wave, occ 2-4 w/SIMD): kernel slice ~55-60us.
//   BW floor arithmetic: 64MiB gather + 64MiB write + 8MiB Wp = 136MiB
//   -> ~22us at 6.3 TB/s. This probes the 2.5x gap.
// __launch_bounds__(256, 4): cap 128 VGPR; hot peak ~90 regs (20 float4
// in flight) fits spill-free; cold branch spills (statistically never runs).
__global__ __launch_bounds__(256, 4)
void blackhole_emb_kernel(const int* __restrict__ ids,
                          const float* __restrict__ vals,
                          const int* __restrict__ fmts,
                          const float* __restrict__ Ww,
                          const float* __restrict__ Wp,
                          const float* __restrict__ Wt,
                          const float* __restrict__ lng,
                          const float* __restrict__ lnb,
                          const float* __restrict__ w1,
                          const float* __restrict__ b1,
                          const float* __restrict__ w2,
                          const float* __restrict__ b2,
                          const float* __restrict__ plng,
                          const float* __restrict__ plnb,
                          float* __restrict__ out,
                          int tokens)
{
    const int lane = threadIdx.x & 63;
    const int wv   = threadIdx.x >> 6;
    const int tok0 = (blockIdx.x * 4 + wv) * 2;
    if (tok0 >= tokens) return;
    const bool has1 = (tok0 + 1) < tokens;
    const int  tok1 = has1 ? tok0 + 1 : tok0;

    const int   id0   = ids[tok0];              // wave-uniform -> s_load
    const int   id1   = ids[tok1];
    const float vraw0 = vals[tok0];
    const float vraw1 = vals[tok1];
    const bool  act0  = (id0 == NUM_TOKEN) && !isnan(vraw0);
    const bool  act1  = has1 && (id1 == NUM_TOKEN) && !isnan(vraw1);

    const float* wrow0 = Ww + (size_t)id0 * HIDDEN;
    const float* prow0 = Wp + (size_t)(tok0 & (SEQ - 1)) * HIDDEN;
    const float* wrow1 = Ww + (size_t)id1 * HIDDEN;
    const float* prow1 = Wp + (size_t)(tok1 & (SEQ - 1)) * HIDDEN;
    const int    col0  = lane * 4;

    // ---- issue ALL 20 loads up front (token0, shared Wt, token1) ----
    float4 a0[4], p0[4], tt[4], a1[4], p1[4];
    #pragma unroll
    for (int j = 0; j < 4; ++j) {
        const int off = j * 256 + col0;
        a0[j] = *(const float4*)(wrow0 + off);
        p0[j] = *(const float4*)(prow0 + off);
        tt[j] = *(const float4*)(Wt    + off);
    }
    #pragma unroll
    for (int j = 0; j < 4; ++j) {
        const int off = j * 256 + col0;
        a1[j] = *(const float4*)(wrow1 + off);
        p1[j] = *(const float4*)(prow1 + off);
    }

    // ---- token 0: combine, (cold MLP), final LN + store ----
    {
        float x[4][4];
        #pragma unroll
        for (int j = 0; j < 4; ++j) {
            x[j][0] = a0[j].x + p0[j].x + tt[j].x;
            x[j][1] = a0[j].y + p0[j].y + tt[j].y;
            x[j][2] = a0[j].z + p0[j].z + tt[j].z;
            x[j][3] = a0[j].w + p0[j].w + tt[j].w;
        }
        if (act0)
            numeric_add(x, vraw0, fmts[tok0], lane, col0, w1, b1, w2, b2, plng, plnb);
        final_ln_store(x, lane, col0, lng, lnb, out + (size_t)tok0 * HIDDEN);
    }

    // ---- token 1 ----
    if (has1) {
        float x[4][4];
        #pragma unroll
        for (int j = 0; j < 4; ++j) {
            x[j][0] = a1[j].x + p1[j].x + tt[j].x;
            x[j][1] = a1[j].y + p1[j].y + tt[j].y;
            x[j][2] = a1[j].z + p1[j].z + tt[j].z;
            x[j][3] = a1[j].w + p1[j].w + tt[j].w;
        }
        if (act1)
            numeric_add(x, vraw1, fmts[tok1], lane, col0, w1, b1, w2, b2, plng, plnb);
        final_ln_store(x, lane, col0, lng, lnb, out + (size_t)tok1 * HIDDEN);
    }
}

extern "C" void kernel_launch(void* const* d_in, const int* in_sizes, int n_in,
                              void* d_out, int out_size, void* d_ws, size_t ws_size,
                              hipStream_t stream) {
    const int*   ids  = (const int*)d_in[0];
    const float* vals = (const float*)d_in[1];
    const int*   fmts = (const int*)d_in[2];
    const float* Ww   = (const float*)d_in[3];
    const float* Wp   = (const float*)d_in[4];
    const float* Wt   = (const float*)d_in[5];
    const float* lng  = (const float*)d_in[6];
    const float* lnb  = (const float*)d_in[7];
    const float* w1   = (const float*)d_in[8];
    const float* b1   = (const float*)d_in[9];
    const float* w2   = (const float*)d_in[10];
    const float* b2   = (const float*)d_in[11];
    const float* plng = (const float*)d_in[12];
    const float* plnb = (const float*)d_in[13];
    float* out = (float*)d_out;

    const int tokens = in_sizes[0];                 // 8 * 2048 = 16384
    const int blocks = (tokens + 7) / 8;            // 4 waves x 2 tokens per block
    blackhole_emb_kernel<<<blocks, 256, 0, stream>>>(
        ids, vals, fmts, Ww, Wp, Wt, lng, lnb, w1, b1, w2, b2, plng, plnb, out, tokens);
}